// Round 1
// baseline (216.455 us; speedup 1.0000x reference)
//
#include <hip/hip_runtime.h>

#define BATCH 8
#define NPTS 2048

// ---------------- kernel 1: zero the 8*16-float accumulator workspace ----------------
__global__ void __launch_bounds__(128) zero_ws_kernel(float* __restrict__ ws) {
    int t = threadIdx.x;
    if (t < BATCH * 16) ws[t] = 0.0f;
}

// ---------------- kernel 2: streaming pass over M ----------------
// Computes per batch b (into ws[b*16 + ...]):
//   [0..8]  S_raw[d*3+e] = sum_n matched[n][d] * Q[n][e]
//   [9..11] sum_n matched[n][d]
// where matched[n] = sum_k M[b,n,k] * P[b,k,:]
// Grid: BATCH*128 blocks of 256 threads (4 waves); each wave owns 4 rows.
__global__ void __launch_bounds__(256) cross_cov_kernel(
        const float* __restrict__ P, const float* __restrict__ Q,
        const float* __restrict__ M, float* __restrict__ ws) {
    __shared__ __attribute__((aligned(16))) float sPx[NPTS];
    __shared__ __attribute__((aligned(16))) float sPy[NPTS];
    __shared__ __attribute__((aligned(16))) float sPz[NPTS];
    __shared__ float partial[4][12];

    const int b = blockIdx.x >> 7;          // 128 blocks per batch
    const int blkInB = blockIdx.x & 127;
    const float* Pb = P + b * NPTS * 3;
    const float* Qb = Q + b * NPTS * 3;
    const float* Mb = M + (size_t)b * NPTS * NPTS;

    // stage P into LDS as SoA (24 KiB)
    for (int k = threadIdx.x; k < NPTS; k += 256) {
        float x = Pb[k * 3 + 0];
        float y = Pb[k * 3 + 1];
        float z = Pb[k * 3 + 2];
        sPx[k] = x; sPy[k] = y; sPz[k] = z;
    }
    __syncthreads();

    const int wave = threadIdx.x >> 6;
    const int lane = threadIdx.x & 63;
    const int row0 = blkInB * 16 + wave * 4;

    float S00 = 0, S01 = 0, S02 = 0, S10 = 0, S11 = 0, S12 = 0, S20 = 0, S21 = 0, S22 = 0;
    float sm0 = 0, sm1 = 0, sm2 = 0;

    for (int r = 0; r < 4; ++r) {
        const int n = row0 + r;
        const float4* Mrow = reinterpret_cast<const float4*>(Mb + (size_t)n * NPTS);
        float ax = 0, ay = 0, az = 0;
#pragma unroll
        for (int it = 0; it < 8; ++it) {
            const int k4 = it * 64 + lane;             // float4 index within row
            float4 m = Mrow[k4];                       // coalesced 16B/lane
            const int k = k4 << 2;
            float4 px = *reinterpret_cast<const float4*>(sPx + k);
            float4 py = *reinterpret_cast<const float4*>(sPy + k);
            float4 pz = *reinterpret_cast<const float4*>(sPz + k);
            ax += m.x * px.x + m.y * px.y + m.z * px.z + m.w * px.w;
            ay += m.x * py.x + m.y * py.y + m.z * py.z + m.w * py.w;
            az += m.x * pz.x + m.y * pz.y + m.z * pz.z + m.w * pz.w;
        }
        // 64-lane butterfly reduction -> all lanes hold row totals
#pragma unroll
        for (int off = 32; off > 0; off >>= 1) {
            ax += __shfl_xor(ax, off);
            ay += __shfl_xor(ay, off);
            az += __shfl_xor(az, off);
        }
        const float qx = Qb[n * 3 + 0];
        const float qy = Qb[n * 3 + 1];
        const float qz = Qb[n * 3 + 2];
        S00 += ax * qx; S01 += ax * qy; S02 += ax * qz;
        S10 += ay * qx; S11 += ay * qy; S12 += ay * qz;
        S20 += az * qx; S21 += az * qy; S22 += az * qz;
        sm0 += ax; sm1 += ay; sm2 += az;
    }

    if (lane == 0) {
        partial[wave][0] = S00; partial[wave][1] = S01; partial[wave][2] = S02;
        partial[wave][3] = S10; partial[wave][4] = S11; partial[wave][5] = S12;
        partial[wave][6] = S20; partial[wave][7] = S21; partial[wave][8] = S22;
        partial[wave][9] = sm0; partial[wave][10] = sm1; partial[wave][11] = sm2;
    }
    __syncthreads();
    if (threadIdx.x < 12) {
        float v = partial[0][threadIdx.x] + partial[1][threadIdx.x] +
                  partial[2][threadIdx.x] + partial[3][threadIdx.x];
        atomicAdd(&ws[b * 16 + threadIdx.x], v);
    }
}

// ---------------- kernel 3: per-batch finalize (means, 3x3 polar, R & t) ----------------
__global__ void __launch_bounds__(256) finalize_kernel(
        const float* __restrict__ P, const float* __restrict__ Q,
        const float* __restrict__ ws, float* __restrict__ out) {
    const int b = blockIdx.x;
    const float* Pb = P + b * NPTS * 3;
    const float* Qb = Q + b * NPTS * 3;

    float px = 0, py = 0, pz = 0, qx = 0, qy = 0, qz = 0;
    for (int k = threadIdx.x; k < NPTS; k += 256) {
        px += Pb[k * 3 + 0]; py += Pb[k * 3 + 1]; pz += Pb[k * 3 + 2];
        qx += Qb[k * 3 + 0]; qy += Qb[k * 3 + 1]; qz += Qb[k * 3 + 2];
    }
#pragma unroll
    for (int off = 32; off > 0; off >>= 1) {
        px += __shfl_xor(px, off); py += __shfl_xor(py, off); pz += __shfl_xor(pz, off);
        qx += __shfl_xor(qx, off); qy += __shfl_xor(qy, off); qz += __shfl_xor(qz, off);
    }
    __shared__ float red[4][6];
    const int wave = threadIdx.x >> 6;
    const int lane = threadIdx.x & 63;
    if (lane == 0) {
        red[wave][0] = px; red[wave][1] = py; red[wave][2] = pz;
        red[wave][3] = qx; red[wave][4] = qy; red[wave][5] = qz;
    }
    __syncthreads();
    if (threadIdx.x == 0) {
        double sp[3], sq[3];
        for (int i = 0; i < 3; ++i) {
            sp[i] = (double)red[0][i] + red[1][i] + red[2][i] + red[3][i];
            sq[i] = (double)red[0][3 + i] + red[1][3 + i] + red[2][3 + i] + red[3][3 + i];
        }
        const float* w = ws + b * 16;
        double smv[3];
        for (int i = 0; i < 3; ++i) smv[i] = (double)w[9 + i];
        // S[d][e] = S_raw[d][e] - sum_matched[d]*sum_Q[e]/N   (mean-centering correction)
        double Sm[9];
        for (int d = 0; d < 3; ++d)
            for (int e = 0; e < 3; ++e)
                Sm[d * 3 + e] = (double)w[d * 3 + e] - smv[d] * sq[e] / (double)NPTS;

        // R = V U^T = orthogonal polar factor of A = S^T.
        // Scaled Newton: X <- 0.5*(g*X + (1/g)*X^{-T}), g=(||X^-1||_F/||X||_F)^{1/2}
        double X[9];
        for (int i = 0; i < 3; ++i)
            for (int j = 0; j < 3; ++j)
                X[i * 3 + j] = Sm[j * 3 + i];
        for (int iter = 0; iter < 20; ++iter) {
            double a0 = X[0], a1 = X[1], a2 = X[2];
            double a3 = X[3], a4 = X[4], a5 = X[5];
            double a6 = X[6], a7 = X[7], a8 = X[8];
            double c0 = a4 * a8 - a5 * a7;
            double c1 = a5 * a6 - a3 * a8;
            double c2 = a3 * a7 - a4 * a6;
            double det = a0 * c0 + a1 * c1 + a2 * c2;
            double invdet = 1.0 / det;
            double inv[9];
            inv[0] = c0 * invdet; inv[1] = (a2 * a7 - a1 * a8) * invdet; inv[2] = (a1 * a5 - a2 * a4) * invdet;
            inv[3] = c1 * invdet; inv[4] = (a0 * a8 - a2 * a6) * invdet; inv[5] = (a2 * a3 - a0 * a5) * invdet;
            inv[6] = c2 * invdet; inv[7] = (a1 * a6 - a0 * a7) * invdet; inv[8] = (a0 * a4 - a1 * a3) * invdet;
            double fx = 0, fi = 0;
            for (int i = 0; i < 9; ++i) { fx += X[i] * X[i]; fi += inv[i] * inv[i]; }
            double g = sqrt(sqrt(fi / fx));       // (||inv||_F/||X||_F)^(1/2)
            double Xn[9];
            for (int i = 0; i < 3; ++i)
                for (int j = 0; j < 3; ++j)
                    Xn[i * 3 + j] = 0.5 * (g * X[i * 3 + j] + inv[j * 3 + i] / g);
            for (int i = 0; i < 9; ++i) X[i] = Xn[i];
        }
        // write R
        for (int i = 0; i < 9; ++i) out[b * 9 + i] = (float)X[i];
        // t = mean(Q) - R * mean(P)
        double mpx = sp[0] / NPTS, mpy = sp[1] / NPTS, mpz = sp[2] / NPTS;
        for (int d = 0; d < 3; ++d) {
            double td = sq[d] / NPTS - (X[d * 3 + 0] * mpx + X[d * 3 + 1] * mpy + X[d * 3 + 2] * mpz);
            out[BATCH * 9 + b * 3 + d] = (float)td;
        }
    }
}

extern "C" void kernel_launch(void* const* d_in, const int* in_sizes, int n_in,
                              void* d_out, int out_size, void* d_ws, size_t ws_size,
                              hipStream_t stream) {
    const float* P = (const float*)d_in[0];   // Ppc [8,2048,3] f32
    const float* Q = (const float*)d_in[1];   // Qpc [8,2048,3] f32
    const float* M = (const float*)d_in[2];   // M   [8,2048,2048] f32
    float* out = (float*)d_out;               // R [8,3,3] ++ t [8,3] = 96 f32
    float* ws = (float*)d_ws;                 // 8*16 floats of accumulators

    zero_ws_kernel<<<1, 128, 0, stream>>>(ws);
    cross_cov_kernel<<<BATCH * 128, 256, 0, stream>>>(P, Q, M, ws);
    finalize_kernel<<<BATCH, 256, 0, stream>>>(P, Q, ws, out);
}

// Round 2
// 214.463 us; speedup vs baseline: 1.0093x; 1.0093x over previous
//
#include <hip/hip_runtime.h>

#define BATCH 8
#define NPTS 2048
#define BLOCKS_PER_BATCH 128
#define ROWS_PER_BLOCK 16   // NPTS / BLOCKS_PER_BATCH

// ---------------- kernel 1: streaming pass over M (column-accumulation form) ----
// S[d,e] = sum_k P[k,d] * T[k,e],  T[k,e] = sum_n M[n,k] * Q[n,e]
// sum_matched[d] = sum_k P[k,d] * colsum[k]
// Each block owns ROWS_PER_BLOCK rows x all 2048 columns. Thread t owns float4
// column groups {t, t+256} (512 float4 cols total). Zero cross-lane traffic in
// the hot loop; one 12-value block reduction at the end; partials to ws.
__global__ void __launch_bounds__(256) cross_cov_kernel(
        const float* __restrict__ P, const float* __restrict__ Q,
        const float* __restrict__ M, float* __restrict__ ws) {
    __shared__ float sQ[ROWS_PER_BLOCK * 3];
    __shared__ float partial[4][12];

    const int b = blockIdx.x >> 7;           // BLOCKS_PER_BATCH = 128
    const int blkInB = blockIdx.x & 127;
    const int n0 = blkInB * ROWS_PER_BLOCK;
    const float* Pb = P + b * NPTS * 3;
    const float* Qb = Q + b * NPTS * 3;
    const float* Mb = M + (size_t)b * NPTS * NPTS;

    const int t = threadIdx.x;
    if (t < ROWS_PER_BLOCK * 3) sQ[t] = Qb[n0 * 3 + t];
    __syncthreads();

    // accumulators: 2 column groups x 4 cols x (T[3] + colsum) = 32 regs
    float T0[4][3] = {}, T1[4][3] = {};
    float cs0[4] = {}, cs1[4] = {};

    const float4* Mrow0 = reinterpret_cast<const float4*>(Mb + (size_t)n0 * NPTS) + t;
    const float4* Mrow1 = Mrow0 + 256;

#pragma unroll 4
    for (int r = 0; r < ROWS_PER_BLOCK; ++r) {
        const float4 m0 = Mrow0[(size_t)r * 512];   // row stride = 2048 floats = 512 float4
        const float4 m1 = Mrow1[(size_t)r * 512];
        const float q0 = sQ[r * 3 + 0];
        const float q1 = sQ[r * 3 + 1];
        const float q2 = sQ[r * 3 + 2];
        T0[0][0] += m0.x * q0; T0[0][1] += m0.x * q1; T0[0][2] += m0.x * q2; cs0[0] += m0.x;
        T0[1][0] += m0.y * q0; T0[1][1] += m0.y * q1; T0[1][2] += m0.y * q2; cs0[1] += m0.y;
        T0[2][0] += m0.z * q0; T0[2][1] += m0.z * q1; T0[2][2] += m0.z * q2; cs0[2] += m0.z;
        T0[3][0] += m0.w * q0; T0[3][1] += m0.w * q1; T0[3][2] += m0.w * q2; cs0[3] += m0.w;
        T1[0][0] += m1.x * q0; T1[0][1] += m1.x * q1; T1[0][2] += m1.x * q2; cs1[0] += m1.x;
        T1[1][0] += m1.y * q0; T1[1][1] += m1.y * q1; T1[1][2] += m1.y * q2; cs1[1] += m1.y;
        T1[2][0] += m1.z * q0; T1[2][1] += m1.z * q1; T1[2][2] += m1.z * q2; cs1[2] += m1.z;
        T1[3][0] += m1.w * q0; T1[3][1] += m1.w * q1; T1[3][2] += m1.w * q2; cs1[3] += m1.w;
    }

    // fold in P: columns k0 = 4t .. 4t+3 and k1 = 4(t+256) ..
    float acc[12];
#pragma unroll
    for (int i = 0; i < 12; ++i) acc[i] = 0.0f;
    {
        const int k0 = 4 * t;
        const int k1 = 4 * (t + 256);
        const float* p0 = Pb + k0 * 3;     // 12 consecutive floats, 16B-aligned
        const float* p1 = Pb + k1 * 3;
#pragma unroll
        for (int j = 0; j < 4; ++j) {
            const float pd0 = p0[j * 3 + 0], pd1 = p0[j * 3 + 1], pd2 = p0[j * 3 + 2];
#pragma unroll
            for (int e = 0; e < 3; ++e) {
                acc[0 + e] += pd0 * T0[j][e];
                acc[3 + e] += pd1 * T0[j][e];
                acc[6 + e] += pd2 * T0[j][e];
            }
            acc[9]  += pd0 * cs0[j];
            acc[10] += pd1 * cs0[j];
            acc[11] += pd2 * cs0[j];
        }
#pragma unroll
        for (int j = 0; j < 4; ++j) {
            const float pd0 = p1[j * 3 + 0], pd1 = p1[j * 3 + 1], pd2 = p1[j * 3 + 2];
#pragma unroll
            for (int e = 0; e < 3; ++e) {
                acc[0 + e] += pd0 * T1[j][e];
                acc[3 + e] += pd1 * T1[j][e];
                acc[6 + e] += pd2 * T1[j][e];
            }
            acc[9]  += pd0 * cs1[j];
            acc[10] += pd1 * cs1[j];
            acc[11] += pd2 * cs1[j];
        }
    }

    // block reduction of 12 values: wave butterfly (once per block), then LDS
#pragma unroll
    for (int off = 32; off > 0; off >>= 1) {
#pragma unroll
        for (int i = 0; i < 12; ++i) acc[i] += __shfl_xor(acc[i], off);
    }
    const int wave = t >> 6;
    const int lane = t & 63;
    if (lane == 0) {
#pragma unroll
        for (int i = 0; i < 12; ++i) partial[wave][i] = acc[i];
    }
    __syncthreads();
    if (t < 12) {
        float v = partial[0][t] + partial[1][t] + partial[2][t] + partial[3][t];
        ws[(size_t)blockIdx.x * 12 + t] = v;   // per-block partial, no atomics
    }
}

// ---------------- kernel 2: reduce partials + means + 3x3 polar -> R, t ----------
__global__ void __launch_bounds__(256) finalize_kernel(
        const float* __restrict__ P, const float* __restrict__ Q,
        const float* __restrict__ ws, float* __restrict__ out) {
    const int b = blockIdx.x;
    const float* Pb = P + b * NPTS * 3;
    const float* Qb = Q + b * NPTS * 3;
    const int t = threadIdx.x;
    const int wave = t >> 6;
    const int lane = t & 63;

    __shared__ float redS[2][12];
    __shared__ float red[4][6];

    // ---- reduce the 128 per-block partials of this batch (threads 0..127) ----
    if (t < BLOCKS_PER_BATCH) {
        const float4* p4 = reinterpret_cast<const float4*>(
            ws + ((size_t)b * BLOCKS_PER_BATCH + t) * 12);
        float4 a = p4[0], c = p4[1], d = p4[2];
        float v[12] = { a.x, a.y, a.z, a.w, c.x, c.y, c.z, c.w, d.x, d.y, d.z, d.w };
#pragma unroll
        for (int off = 32; off > 0; off >>= 1) {
#pragma unroll
            for (int i = 0; i < 12; ++i) v[i] += __shfl_xor(v[i], off);
        }
        if (lane == 0) {
#pragma unroll
            for (int i = 0; i < 12; ++i) redS[wave][i] = v[i];
        }
    }

    // ---- P/Q column sums (all 256 threads) ----
    float px = 0, py = 0, pz = 0, qx = 0, qy = 0, qz = 0;
    for (int k = t; k < NPTS; k += 256) {
        px += Pb[k * 3 + 0]; py += Pb[k * 3 + 1]; pz += Pb[k * 3 + 2];
        qx += Qb[k * 3 + 0]; qy += Qb[k * 3 + 1]; qz += Qb[k * 3 + 2];
    }
#pragma unroll
    for (int off = 32; off > 0; off >>= 1) {
        px += __shfl_xor(px, off); py += __shfl_xor(py, off); pz += __shfl_xor(pz, off);
        qx += __shfl_xor(qx, off); qy += __shfl_xor(qy, off); qz += __shfl_xor(qz, off);
    }
    if (lane == 0) {
        red[wave][0] = px; red[wave][1] = py; red[wave][2] = pz;
        red[wave][3] = qx; red[wave][4] = qy; red[wave][5] = qz;
    }
    __syncthreads();

    if (t == 0) {
        double sp[3], sq[3];
        for (int i = 0; i < 3; ++i) {
            sp[i] = (double)red[0][i] + red[1][i] + red[2][i] + red[3][i];
            sq[i] = (double)red[0][3 + i] + red[1][3 + i] + red[2][3 + i] + red[3][3 + i];
        }
        double w[12];
        for (int i = 0; i < 12; ++i) w[i] = (double)redS[0][i] + (double)redS[1][i];

        // S[d][e] = S_raw[d][e] - sum_matched[d]*sum_Q[e]/N
        double Sm[9];
        for (int d = 0; d < 3; ++d)
            for (int e = 0; e < 3; ++e)
                Sm[d * 3 + e] = w[d * 3 + e] - w[9 + d] * sq[e] / (double)NPTS;

        // R = V U^T = orthogonal polar factor of A = S^T (scaled Newton iteration)
        double X[9];
        for (int i = 0; i < 3; ++i)
            for (int j = 0; j < 3; ++j)
                X[i * 3 + j] = Sm[j * 3 + i];
        for (int iter = 0; iter < 20; ++iter) {
            double a0 = X[0], a1 = X[1], a2 = X[2];
            double a3 = X[3], a4 = X[4], a5 = X[5];
            double a6 = X[6], a7 = X[7], a8 = X[8];
            double c0 = a4 * a8 - a5 * a7;
            double c1 = a5 * a6 - a3 * a8;
            double c2 = a3 * a7 - a4 * a6;
            double det = a0 * c0 + a1 * c1 + a2 * c2;
            double invdet = 1.0 / det;
            double inv[9];
            inv[0] = c0 * invdet; inv[1] = (a2 * a7 - a1 * a8) * invdet; inv[2] = (a1 * a5 - a2 * a4) * invdet;
            inv[3] = c1 * invdet; inv[4] = (a0 * a8 - a2 * a6) * invdet; inv[5] = (a2 * a3 - a0 * a5) * invdet;
            inv[6] = c2 * invdet; inv[7] = (a1 * a6 - a0 * a7) * invdet; inv[8] = (a0 * a4 - a1 * a3) * invdet;
            double fx = 0, fi = 0;
            for (int i = 0; i < 9; ++i) { fx += X[i] * X[i]; fi += inv[i] * inv[i]; }
            double g = sqrt(sqrt(fi / fx));
            double Xn[9];
            for (int i = 0; i < 3; ++i)
                for (int j = 0; j < 3; ++j)
                    Xn[i * 3 + j] = 0.5 * (g * X[i * 3 + j] + inv[j * 3 + i] / g);
            for (int i = 0; i < 9; ++i) X[i] = Xn[i];
        }
        for (int i = 0; i < 9; ++i) out[b * 9 + i] = (float)X[i];
        double mpx = sp[0] / NPTS, mpy = sp[1] / NPTS, mpz = sp[2] / NPTS;
        for (int d = 0; d < 3; ++d) {
            double td = sq[d] / NPTS - (X[d * 3 + 0] * mpx + X[d * 3 + 1] * mpy + X[d * 3 + 2] * mpz);
            out[BATCH * 9 + b * 3 + d] = (float)td;
        }
    }
}

extern "C" void kernel_launch(void* const* d_in, const int* in_sizes, int n_in,
                              void* d_out, int out_size, void* d_ws, size_t ws_size,
                              hipStream_t stream) {
    const float* P = (const float*)d_in[0];   // Ppc [8,2048,3] f32
    const float* Q = (const float*)d_in[1];   // Qpc [8,2048,3] f32
    const float* M = (const float*)d_in[2];   // M   [8,2048,2048] f32
    float* out = (float*)d_out;               // R [8,3,3] ++ t [8,3] = 96 f32
    float* ws = (float*)d_ws;                 // per-block partials: 1024*12 f32

    cross_cov_kernel<<<BATCH * BLOCKS_PER_BATCH, 256, 0, stream>>>(P, Q, M, ws);
    finalize_kernel<<<BATCH, 256, 0, stream>>>(P, Q, ws, out);
}